// Round 2
// baseline (3519.036 us; speedup 1.0000x reference)
//
#include <hip/hip_runtime.h>

#define HH 6144
#define WW 6144
#define KH 11
#define KW 11
#define OH (HH - KH + 1)   // 6134
#define OW (WW - KW + 1)   // 6134

#define BX 256                    // output cols per block
#define BY 16                     // output rows per block
#define LROWS (BY + KH - 1)       // 26 input rows staged
#define LSTR 272                  // LDS row stride in dwords (need 266)
#define NCH 67                    // float4 chunks staged per row (268 dwords)
#define TOT_CH (LROWS * NCH)      // 1742

#define TILES_X ((OW + BX - 1) / BX)   // 24
#define TILES_Y ((OH + BY - 1) / BY)   // 384
#define NWG (TILES_X * TILES_Y)        // 9216
#define XCDS 8
#define COLS_PER_XCD (TILES_X / XCDS)  // 3 tile-columns per XCD

__global__ __launch_bounds__(256, 4)
void conv2d_11x11_kernel(const float* __restrict__ X,
                         const float* __restrict__ Wt,
                         const float* __restrict__ bias,
                         float* __restrict__ out)
{
    __shared__ float tile[LROWS][LSTR];

    // ---- XCD-aware remap: XCD k owns tile-columns 3k..3k+2, column-major ----
    const int bid = (int)blockIdx.x;
    const int xcd = bid & 7;
    const int loc = bid >> 3;                   // 0..1151
    const int txt = xcd * COLS_PER_XCD + loc / TILES_Y;
    const int tyt = loc % TILES_Y;

    const int x0 = txt * BX;
    const int y0 = tyt * BY;
    const int tid = (int)threadIdx.x;

    // ---------------- stage input tile (vectorized, clamped) ----------------
    #pragma unroll
    for (int it = 0; it < 7; ++it) {
        const int idx = it * 256 + tid;
        if (idx < TOT_CH) {
            const int row = idx / NCH;
            const int c4  = idx - row * NCH;
            const int gy  = y0 + row;
            const int gx  = x0 + c4 * 4;
            float4 v;
            if (gy < HH && gx + 3 < WW) {
                v = *reinterpret_cast<const float4*>(&X[(size_t)gy * WW + gx]);
            } else {
                v.x = (gy < HH && gx + 0 < WW) ? X[(size_t)gy * WW + gx + 0] : 0.f;
                v.y = (gy < HH && gx + 1 < WW) ? X[(size_t)gy * WW + gx + 1] : 0.f;
                v.z = (gy < HH && gx + 2 < WW) ? X[(size_t)gy * WW + gx + 2] : 0.f;
                v.w = (gy < HH && gx + 3 < WW) ? X[(size_t)gy * WW + gx + 3] : 0.f;
            }
            *reinterpret_cast<float4*>(&tile[row][c4 * 4]) = v;
        }
    }

    // ---- weights: uniform loads -> SGPRs (1 SGPR operand per v_fmac ok) ----
    float Wr[KH * KW];
    #pragma unroll
    for (int t = 0; t < KH * KW; ++t) Wr[t] = Wt[t];
    const float bv = bias[0];

    // ---------------- per-thread mapping: 4 rows x 4 cols --------------------
    const int lane = tid & 63;      // 64 lanes span one row => conflict-free LDS
    const int ty   = tid >> 6;      // 4 row-groups
    const int lx   = lane * 4;
    const int ly   = ty * 4;

    float acc[4][4];
    #pragma unroll
    for (int r = 0; r < 4; ++r)
        #pragma unroll
        for (int c = 0; c < 4; ++c) acc[r][c] = bv;   // fold bias

    __syncthreads();

    #pragma unroll
    for (int di = 0; di < KH + 3; ++di) {             // 14 input rows
        float xs[16];
        #pragma unroll
        for (int k = 0; k < 4; ++k) {
            float4 v = *reinterpret_cast<const float4*>(&tile[ly + di][lx + 4 * k]);
            xs[4 * k + 0] = v.x; xs[4 * k + 1] = v.y;
            xs[4 * k + 2] = v.z; xs[4 * k + 3] = v.w;
        }
        #pragma unroll
        for (int r = 0; r < 4; ++r) {
            const int ki = di - r;                    // constant after unroll
            if (ki < 0 || ki > KH - 1) continue;
            #pragma unroll
            for (int dj = 0; dj < KW; ++dj) {
                const float w = Wr[ki * KW + dj];
                #pragma unroll
                for (int c = 0; c < 4; ++c)
                    acc[r][c] += xs[dj + c] * w;
            }
        }
    }

    // ---------------- store (float2, 8B-aligned; guarded at edges) ----------
    const int ox0 = x0 + lx;
    const int oy0 = y0 + ly;
    #pragma unroll
    for (int r = 0; r < 4; ++r) {
        const int oy = oy0 + r;
        if (oy >= OH) break;
        const size_t base = (size_t)oy * OW + ox0;
        if (ox0 + 3 < OW) {
            float2 a, b;
            a.x = acc[r][0]; a.y = acc[r][1];
            b.x = acc[r][2]; b.y = acc[r][3];
            *reinterpret_cast<float2*>(&out[base + 0]) = a;
            *reinterpret_cast<float2*>(&out[base + 2]) = b;
        } else {
            #pragma unroll
            for (int c = 0; c < 4; ++c)
                if (ox0 + c < OW) out[base + c] = acc[r][c];
        }
    }
}

extern "C" void kernel_launch(void* const* d_in, const int* in_sizes, int n_in,
                              void* d_out, int out_size, void* d_ws, size_t ws_size,
                              hipStream_t stream) {
    const float* X    = (const float*)d_in[0];
    const float* Wt   = (const float*)d_in[1];
    const float* bias = (const float*)d_in[2];
    float* out        = (float*)d_out;

    conv2d_11x11_kernel<<<dim3(NWG), dim3(256), 0, stream>>>(X, Wt, bias, out);
}

// Round 3
// 156.773 us; speedup vs baseline: 22.4466x; 22.4466x over previous
//
#include <hip/hip_runtime.h>

#define HH 6144
#define WW 6144
#define KH 11
#define KW 11
#define OH (HH - KH + 1)   // 6134
#define OW (WW - KW + 1)   // 6134

#define BX 256                    // output cols per block
#define BY 16                     // output rows per block
#define LROWS (BY + KH - 1)       // 26 input rows staged
#define LSTR 272                  // LDS row stride in dwords
#define NCH 67                    // float4 chunks per row (268 dwords >= 266 needed)
#define TOT_CH (LROWS * NCH)      // 1742

#define TILES_X 24
#define TILES_Y 384
#define NWG (TILES_X * TILES_Y)   // 9216
#define COLS_PER_XCD 3

__global__ __launch_bounds__(256, 4)
void conv2d_11x11_kernel(const float* __restrict__ X,
                         const float* __restrict__ Wt,
                         const float* __restrict__ bias,
                         float* __restrict__ out)
{
    __shared__ float tile[LROWS][LSTR];

    // XCD-aware remap: XCD k owns tile-columns 3k..3k+2, traversed column-major
    // so vertically-adjacent blocks (sharing 10 halo rows) land on the same L2.
    const int bid = (int)blockIdx.x;
    const int xcd = bid & 7;
    const int loc = bid >> 3;
    const int txt = xcd * COLS_PER_XCD + loc / TILES_Y;
    const int tyt = loc % TILES_Y;

    const int x0 = txt * BX;
    const int y0 = tyt * BY;
    const int tid = (int)threadIdx.x;

    // ---------------- stage input tile (vectorized, clamped) ----------------
    #pragma unroll
    for (int it = 0; it < 7; ++it) {
        const int idx = it * 256 + tid;
        if (idx < TOT_CH) {
            const int row = idx / NCH;
            const int c4  = idx - row * NCH;
            const int gy  = y0 + row;
            const int gx  = x0 + c4 * 4;
            float4 v;
            if (gy < HH && gx + 3 < WW) {
                v = *reinterpret_cast<const float4*>(&X[(size_t)gy * WW + gx]);
            } else {
                v.x = (gy < HH && gx + 0 < WW) ? X[(size_t)gy * WW + gx + 0] : 0.f;
                v.y = (gy < HH && gx + 1 < WW) ? X[(size_t)gy * WW + gx + 1] : 0.f;
                v.z = (gy < HH && gx + 2 < WW) ? X[(size_t)gy * WW + gx + 2] : 0.f;
                v.w = (gy < HH && gx + 3 < WW) ? X[(size_t)gy * WW + gx + 3] : 0.f;
            }
            *reinterpret_cast<float4*>(&tile[row][c4 * 4]) = v;
        }
    }

    const float bv = bias[0];

    // per-thread mapping: 64 lanes span one full row (conflict-free b128 reads)
    const int lane = tid & 63;
    const int ty   = tid >> 6;
    const int lx   = lane * 4;
    const int ly   = ty * 4;

    float acc[4][4];
    #pragma unroll
    for (int r = 0; r < 4; ++r)
        #pragma unroll
        for (int c = 0; c < 4; ++c) acc[r][c] = bv;

    __syncthreads();

    // di is a RUNTIME loop: keeps weight addresses runtime -> just-in-time
    // s_load of one 11-weight row per (di,r); <=44 weight SGPRs live, zero
    // VGPR pressure from weights (this is what killed rounds 0/1).
    #pragma unroll 1
    for (int di = 0; di < KH + 3; ++di) {        // 14 input rows
        float xs[16];
        const float* src = &tile[ly + di][lx];
        #pragma unroll
        for (int k = 0; k < 4; ++k) {
            float4 v = *reinterpret_cast<const float4*>(src + 4 * k);
            xs[4 * k + 0] = v.x; xs[4 * k + 1] = v.y;
            xs[4 * k + 2] = v.z; xs[4 * k + 3] = v.w;
        }
        #pragma unroll
        for (int r = 0; r < 4; ++r) {
            const int ki = di - r;               // runtime, wave-uniform
            if (ki < 0 || ki > KH - 1) continue; // uniform scalar branch
            const float* wrow = Wt + ki * KW;
            #pragma unroll
            for (int dj = 0; dj < KW; ++dj) {
                const float w = wrow[dj];        // uniform -> s_load (sL1-hot)
                #pragma unroll
                for (int c = 0; c < 4; ++c)
                    acc[r][c] += xs[dj + c] * w;
            }
        }
    }

    // ---------------- store (float2, 8B-aligned; guarded at edges) ----------
    const int ox0 = x0 + lx;
    const int oy0 = y0 + ly;
    #pragma unroll
    for (int r = 0; r < 4; ++r) {
        const int oy = oy0 + r;
        if (oy >= OH) break;
        const size_t base = (size_t)oy * OW + ox0;
        if (ox0 + 3 < OW) {
            float2 a, b;
            a.x = acc[r][0]; a.y = acc[r][1];
            b.x = acc[r][2]; b.y = acc[r][3];
            *reinterpret_cast<float2*>(&out[base + 0]) = a;
            *reinterpret_cast<float2*>(&out[base + 2]) = b;
        } else {
            #pragma unroll
            for (int c = 0; c < 4; ++c)
                if (ox0 + c < OW) out[base + c] = acc[r][c];
        }
    }
}

extern "C" void kernel_launch(void* const* d_in, const int* in_sizes, int n_in,
                              void* d_out, int out_size, void* d_ws, size_t ws_size,
                              hipStream_t stream) {
    const float* X    = (const float*)d_in[0];
    const float* Wt   = (const float*)d_in[1];
    const float* bias = (const float*)d_in[2];
    float* out        = (float*)d_out;

    conv2d_11x11_kernel<<<dim3(NWG), dim3(256), 0, stream>>>(X, Wt, bias, out);
}

// Round 4
// 142.831 us; speedup vs baseline: 24.6377x; 1.0976x over previous
//
#include <hip/hip_runtime.h>

typedef _Float16 half2_t __attribute__((ext_vector_type(2)));

#define HH 6144
#define WW 6144
#define KH 11
#define KW 11
#define OH (HH - KH + 1)   // 6134
#define OW (WW - KW + 1)   // 6134

#define BX 256                    // output cols per block
#define BY 16                     // output rows per block
#define LROWS (BY + KH - 1)       // 26 input rows staged
#define WSTR 136                  // half2 words per row per copy (need <=134)
#define NCH 67                    // float4 chunks per row (268 floats staged)
#define TOT_CH (LROWS * NCH)      // 1742

#define TILES_X 24
#define TILES_Y 384
#define NWG (TILES_X * TILES_Y)   // 9216
#define COLS_PER_XCD 3

union u32h2 { unsigned int u; half2_t h; };

#if defined(__has_builtin)
#if __has_builtin(__builtin_amdgcn_fdot2)
#define HAVE_FDOT2 1
#endif
#endif
#ifdef HAVE_FDOT2
#define FDOT2(a, b, c) __builtin_amdgcn_fdot2((a), (b), (c), false)
#else
#define FDOT2(a, b, c) ((float)(a).x * (float)(b).x + (float)(a).y * (float)(b).y + (c))
#endif

// ---- prep: pack weight rows into half2 pairs, padded to 6 pairs/row --------
__global__ void pack_weights_kernel(const float* __restrict__ Wt,
                                    unsigned int* __restrict__ wpk) {
    const int t = (int)threadIdx.x;
    if (t < KH * 6) {
        const int ki = t / 6, p = t % 6;
        const float a = Wt[ki * KW + 2 * p];
        const float b = (2 * p + 1 < KW) ? Wt[ki * KW + 2 * p + 1] : 0.f;
        half2_t h;
        h.x = (_Float16)a;     // RTN converts
        h.y = (_Float16)b;
        u32h2 u; u.h = h;
        wpk[t] = u.u;
    }
}

__global__ __launch_bounds__(256, 4)
void conv2d_11x11_dot2_kernel(const float* __restrict__ X,
                              const unsigned int* __restrict__ wpk,
                              const float* __restrict__ bias,
                              float* __restrict__ out)
{
    // copy A: pairs (h0,h1)(h2,h3)...; copy B: pairs (h1,h2)(h3,h4)...
    __shared__ half2_t tileA[LROWS][WSTR];
    __shared__ half2_t tileB[LROWS][WSTR];

    // XCD-aware remap: XCD k owns 3 tile-columns, traversed column-major.
    const int bid = (int)blockIdx.x;
    const int xcd = bid & 7;
    const int loc = bid >> 3;
    const int txt = xcd * COLS_PER_XCD + loc / TILES_Y;
    const int tyt = loc % TILES_Y;

    const int x0 = txt * BX;
    const int y0 = tyt * BY;
    const int tid = (int)threadIdx.x;

    // ---------------- stage both fp16 copies (clamped) ----------------------
    #pragma unroll
    for (int it = 0; it < 7; ++it) {
        const int idx = it * 256 + tid;
        if (idx < TOT_CH) {
            const int row = idx / NCH;
            const int c4  = idx - row * NCH;
            const int gy  = y0 + row;
            const int gx  = x0 + c4 * 4;
            float4 v; float xn;
            if (gy < HH && gx + 4 < WW) {
                v  = *reinterpret_cast<const float4*>(&X[(size_t)gy * WW + gx]);
                xn = X[(size_t)gy * WW + gx + 4];
            } else {
                v.x = (gy < HH && gx + 0 < WW) ? X[(size_t)gy * WW + gx + 0] : 0.f;
                v.y = (gy < HH && gx + 1 < WW) ? X[(size_t)gy * WW + gx + 1] : 0.f;
                v.z = (gy < HH && gx + 2 < WW) ? X[(size_t)gy * WW + gx + 2] : 0.f;
                v.w = (gy < HH && gx + 3 < WW) ? X[(size_t)gy * WW + gx + 3] : 0.f;
                xn  = (gy < HH && gx + 4 < WW) ? X[(size_t)gy * WW + gx + 4] : 0.f;
            }
            const _Float16 h0 = (_Float16)v.x, h1 = (_Float16)v.y;
            const _Float16 h2 = (_Float16)v.z, h3 = (_Float16)v.w;
            const _Float16 h4 = (_Float16)xn;
            half2_t p0; p0.x = h0; p0.y = h1;
            half2_t p1; p1.x = h2; p1.y = h3;
            half2_t q0; q0.x = h1; q0.y = h2;
            half2_t q1; q1.x = h3; q1.y = h4;
            tileA[row][2 * c4 + 0] = p0;
            tileA[row][2 * c4 + 1] = p1;
            tileB[row][2 * c4 + 0] = q0;
            tileB[row][2 * c4 + 1] = q1;
        }
    }

    const float bv = bias[0];

    // 64 lanes span one full row; 4 output cols + 4 output rows per thread
    const int lane = tid & 63;
    const int ty   = tid >> 6;
    const int ly   = ty * 4;

    float acc[4][4];
    #pragma unroll
    for (int r = 0; r < 4; ++r)
        #pragma unroll
        for (int c = 0; c < 4; ++c) acc[r][c] = bv;

    __syncthreads();

    // runtime di loop keeps weight addrs runtime-uniform -> s_load, no VGPR
    // weight array (the round-0/1 spill trap).
    #pragma unroll 1
    for (int di = 0; di < KH + 3; ++di) {            // 14 input rows
        const half2_t* rA = &tileA[ly + di][lane * 2];
        const half2_t* rB = &tileB[ly + di][lane * 2];
        half2_t Ar[7], Br[7];
        #pragma unroll
        for (int t = 0; t < 7; ++t) Ar[t] = rA[t];   // adjacent -> merged ds_reads
        #pragma unroll
        for (int t = 0; t < 7; ++t) Br[t] = rB[t];

        #pragma unroll
        for (int r = 0; r < 4; ++r) {
            const int ki = di - r;                   // wave-uniform
            if (ki < 0 || ki > KH - 1) continue;
            const unsigned int* wq = wpk + ki * 6;
            #pragma unroll
            for (int t = 0; t < 6; ++t) {
                u32h2 wv; wv.u = wq[t];              // uniform -> s_load
                const half2_t wh = wv.h;
                acc[r][0] = FDOT2(Ar[t],     wh, acc[r][0]);  // col lx+0 (even->A)
                acc[r][1] = FDOT2(Br[t],     wh, acc[r][1]);  // col lx+1 (odd ->B)
                acc[r][2] = FDOT2(Ar[t + 1], wh, acc[r][2]);  // col lx+2
                acc[r][3] = FDOT2(Br[t + 1], wh, acc[r][3]);  // col lx+3
            }
        }
    }

    // ---------------- store (float2, 8B-aligned; guarded at edges) ----------
    const int ox0 = x0 + lane * 4;
    const int oy0 = y0 + ly;
    #pragma unroll
    for (int r = 0; r < 4; ++r) {
        const int oy = oy0 + r;
        if (oy >= OH) break;
        const size_t base = (size_t)oy * OW + ox0;
        if (ox0 + 3 < OW) {
            float2 a, b;
            a.x = acc[r][0]; a.y = acc[r][1];
            b.x = acc[r][2]; b.y = acc[r][3];
            *reinterpret_cast<float2*>(&out[base + 0]) = a;
            *reinterpret_cast<float2*>(&out[base + 2]) = b;
        } else {
            #pragma unroll
            for (int c = 0; c < 4; ++c)
                if (ox0 + c < OW) out[base + c] = acc[r][c];
        }
    }
}

extern "C" void kernel_launch(void* const* d_in, const int* in_sizes, int n_in,
                              void* d_out, int out_size, void* d_ws, size_t ws_size,
                              hipStream_t stream) {
    const float* X    = (const float*)d_in[0];
    const float* Wt   = (const float*)d_in[1];
    const float* bias = (const float*)d_in[2];
    float* out        = (float*)d_out;
    unsigned int* wpk = (unsigned int*)d_ws;   // 66 dwords of packed weights

    pack_weights_kernel<<<1, 128, 0, stream>>>(Wt, wpk);
    conv2d_11x11_dot2_kernel<<<dim3(NWG), dim3(256), 0, stream>>>(X, wpk, bias, out);
}

// Round 6
// 114.400 us; speedup vs baseline: 30.7608x; 1.2485x over previous
//
#include <hip/hip_runtime.h>

typedef _Float16 half8 __attribute__((ext_vector_type(8)));
typedef __fp16  fp16x2 __attribute__((ext_vector_type(2)));
typedef float f32x4 __attribute__((ext_vector_type(4)));

#define HH 6144
#define WW 6144
#define KH 11
#define KW 11
#define OH (HH - KH + 1)   // 6134
#define OW (WW - KW + 1)   // 6134

#define BROWS 32           // out rows per block
#define BCOLS 128          // out cols per block
#define SROWS 48           // staged input rows (p = 0..47)
#define SCOLS 144          // staged input cols (need 138)
#define CSTR 80            // halves per LDS column (160 B): balanced banks for b128 reads

#define AK 352             // K extent: 11 kj * 32 p-slots
#define TILES_X 48         // 6134/128 -> 48
#define TILES_Y 192        // 6134/32  -> 192
#define NWG (TILES_X * TILES_Y)   // 9216

// ---- prep: banded weight matrix A[16][352], A[i][kj*32+p] = W[p-i][kj] ----
__global__ void build_A_kernel(const float* __restrict__ Wt,
                               _Float16* __restrict__ Amat) {
    const int t = (int)blockIdx.x * 256 + (int)threadIdx.x;
    if (t < 16 * AK) {
        const int m = t / AK;
        const int k = t - m * AK;
        const int kj = k >> 5;          // 0..10
        const int p  = k & 31;          // 0..31
        const int ki = p - m;
        float v = (ki >= 0 && ki <= KH - 1) ? Wt[ki * KW + kj] : 0.f;
        Amat[t] = (_Float16)v;          // RNE
    }
}

union pk2 { fp16x2 h; unsigned int u; };

static __device__ inline unsigned int cvt2(float a, float b) {
#if defined(__has_builtin) && __has_builtin(__builtin_amdgcn_cvt_pkrtz)
    pk2 r; r.h = __builtin_amdgcn_cvt_pkrtz(a, b);
    return r.u;
#else
    pk2 r; r.h[0] = (__fp16)a; r.h[1] = (__fp16)b;
    return r.u;
#endif
}

__global__ __launch_bounds__(256, 4)
void conv2d_mfma_kernel(const float* __restrict__ X,
                        const _Float16* __restrict__ Amat,
                        const float* __restrict__ bias,
                        float* __restrict__ out)
{
    // column-major fp16 X tile: element (p, c) at lds[c*CSTR + p]
    __shared__ _Float16 lds[SCOLS * CSTR];   // 23040 B

    // XCD-aware remap: XCD k owns 6 tile-columns, traversed column-major.
    const int bid = (int)blockIdx.x;
    const int xcd = bid & 7;
    const int loc = bid >> 3;                 // 0..1151
    const int txt = xcd * 6 + loc / TILES_Y;  // 0..47
    const int tyt = loc % TILES_Y;            // 0..191

    const int x0 = txt * BCOLS;
    const int y0 = tyt * BROWS;
    const int tid = (int)threadIdx.x;
    const int lane = tid & 63;
    const int n = lane & 15;                  // MFMA col / B-col lane role
    const int h = lane >> 4;                  // k-group lane role
    const int w = tid >> 6;                   // wave id: cols w*32..w*32+31

    // ---- A fragments: lane reads A[m=n][k = kb*32 + h*8 + e] (16B each) ----
    const _Float16* ap = Amat + n * AK + h * 8;
    half8 Af[11];
    #pragma unroll
    for (int kb = 0; kb < 11; ++kb)
        Af[kb] = *reinterpret_cast<const half8*>(ap + kb * 32);

    const float bv = bias[0];

    // ---- stage X tile, transposed to col-major fp16 ------------------------
    // task = (col cc, row-chunk rc): consecutive threads -> consecutive cols
    // (coalesced global loads; LDS b64 writes spread over 4 bank-windows).
    #pragma unroll
    for (int it = 0; it < 7; ++it) {
        const int idx = it * 256 + tid;
        if (idx < SCOLS * (SROWS / 4)) {      // 144 * 12 = 1728
            const int rc = idx / SCOLS;       // 0..11
            const int cc = idx - rc * SCOLS;  // 0..143
            const int gx = x0 + cc;
            const int gyb = y0 + rc * 4;
            float v0 = 0.f, v1 = 0.f, v2 = 0.f, v3 = 0.f;
            if (gx < WW) {
                const float* col = X + gx;
                if (gyb + 0 < HH) v0 = col[(size_t)(gyb + 0) * WW];
                if (gyb + 1 < HH) v1 = col[(size_t)(gyb + 1) * WW];
                if (gyb + 2 < HH) v2 = col[(size_t)(gyb + 2) * WW];
                if (gyb + 3 < HH) v3 = col[(size_t)(gyb + 3) * WW];
            }
            uint2 pk;
            pk.x = cvt2(v0, v1);
            pk.y = cvt2(v2, v3);
            *reinterpret_cast<uint2*>(&lds[cc * CSTR + rc * 4]) = pk;
        }
    }

    f32x4 acc00 = {bv, bv, bv, bv};   // (t=0, rt=0)
    f32x4 acc01 = {bv, bv, bv, bv};   // (t=0, rt=1)
    f32x4 acc10 = {bv, bv, bv, bv};   // (t=1, rt=0)
    f32x4 acc11 = {bv, bv, bv, bv};   // (t=1, rt=1)

    __syncthreads();

    // ---- main compute: B-frag = one b128 per MFMA, zero per-read VALU ------
    // byte addr = (w*32 + n + 16t + kb)*160 + rt*32 + h*16
    const char* p0 = reinterpret_cast<const char*>(lds) + (w * 32 + n) * (CSTR * 2) + h * 16;
    #pragma unroll
    for (int kb = 0; kb < 11; ++kb) {
        const int cofs = kb * (CSTR * 2);
        half8 b00 = *reinterpret_cast<const half8*>(p0 + cofs);
        half8 b01 = *reinterpret_cast<const half8*>(p0 + cofs + 32);
        half8 b10 = *reinterpret_cast<const half8*>(p0 + cofs + 16 * (CSTR * 2));
        half8 b11 = *reinterpret_cast<const half8*>(p0 + cofs + 16 * (CSTR * 2) + 32);
        acc00 = __builtin_amdgcn_mfma_f32_16x16x32_f16(Af[kb], b00, acc00, 0, 0, 0);
        acc01 = __builtin_amdgcn_mfma_f32_16x16x32_f16(Af[kb], b01, acc01, 0, 0, 0);
        acc10 = __builtin_amdgcn_mfma_f32_16x16x32_f16(Af[kb], b10, acc10, 0, 0, 0);
        acc11 = __builtin_amdgcn_mfma_f32_16x16x32_f16(Af[kb], b11, acc11, 0, 0, 0);
    }

    // ---- store: D col = lane&15, row = h*4 + reg ---------------------------
    const int colb = x0 + w * 32 + n;
    #pragma unroll
    for (int r = 0; r < 4; ++r) {
        const int row0 = y0 + h * 4 + r;         // rt = 0
        const int row1 = row0 + 16;              // rt = 1
        if (row0 < OH) {
            if (colb      < OW) out[(size_t)row0 * OW + colb]      = acc00[r];
            if (colb + 16 < OW) out[(size_t)row0 * OW + colb + 16] = acc10[r];
        }
        if (row1 < OH) {
            if (colb      < OW) out[(size_t)row1 * OW + colb]      = acc01[r];
            if (colb + 16 < OW) out[(size_t)row1 * OW + colb + 16] = acc11[r];
        }
    }
}

extern "C" void kernel_launch(void* const* d_in, const int* in_sizes, int n_in,
                              void* d_out, int out_size, void* d_ws, size_t ws_size,
                              hipStream_t stream) {
    const float* X    = (const float*)d_in[0];
    const float* Wt   = (const float*)d_in[1];
    const float* bias = (const float*)d_in[2];
    float* out        = (float*)d_out;
    _Float16* Amat    = (_Float16*)d_ws;      // 16*352*2 = 11264 B

    build_A_kernel<<<dim3(22), dim3(256), 0, stream>>>(Wt, Amat);
    conv2d_mfma_kernel<<<dim3(NWG), dim3(256), 0, stream>>>(X, Amat, bias, out);
}